// Round 1
// baseline (624.823 us; speedup 1.0000x reference)
//
#include <hip/hip_runtime.h>
#include <hip/hip_bf16.h>

#define T_DIM 2048
#define B_DIM 16
#define D_DIM 1024
#define M_DIM (T_DIM * B_DIM)   // 32768 GEMM rows
#define K_DIM D_DIM             // 1024
#define N_DIM (3 * D_DIM)       // 3072 (cand_x | delta | gate)
#define BD (B_DIM * D_DIM)      // 16384 parallel chains
#define CHUNKS 64
#define CLEN (T_DIM / CHUNKS)   // 32

typedef __attribute__((ext_vector_type(8))) short bf16x8;
typedef __attribute__((ext_vector_type(4))) float f32x4;
typedef __attribute__((ext_vector_type(4))) unsigned short us4;

__device__ __forceinline__ unsigned short f2bf(float f) {
    unsigned int u = __builtin_bit_cast(unsigned int, f);
    u += 0x7fffu + ((u >> 16) & 1u);  // RNE
    return (unsigned short)(u >> 16);
}
__device__ __forceinline__ float bf2f(unsigned short s) {
    unsigned int u = ((unsigned int)s) << 16;
    return __builtin_bit_cast(float, u);
}
__device__ __forceinline__ float sigmoid_f(float x) {
    return __builtin_amdgcn_rcpf(1.0f + __expf(-x));
}
__device__ __forceinline__ float tanh_f(float x) {
    float e = __expf(2.0f * x);
    return 1.0f - 2.0f * __builtin_amdgcn_rcpf(e + 1.0f);
}

// ---------------------------------------------------------------------------
// Fused projection GEMM: Y[m,n] = sum_k x[m,k] * W[n,k]  (+bias, activation)
// n in [0,1024): cand_x (identity + b)        -> cxw  bf16
// n in [1024,2048): delta (sigmoid + b_delta) -> dw   bf16
// n in [2048,3072): gate (silu + b_gate)      -> gw   bf16
// 128x128 tile, BK=32, 4 waves (2x2), 16x16x32 bf16 MFMA, reg-staged fp32->bf16.
// ---------------------------------------------------------------------------
__global__ __launch_bounds__(256, 2)
void gemm_fused(const float* __restrict__ x,
                const float* __restrict__ Wx, const float* __restrict__ Wd,
                const float* __restrict__ Wg,
                const float* __restrict__ bx, const float* __restrict__ bdl,
                const float* __restrict__ bg,
                unsigned short* __restrict__ cxw, unsigned short* __restrict__ dw,
                unsigned short* __restrict__ gw)
{
    __shared__ unsigned short ldsA[128 * 32];
    __shared__ unsigned short ldsB[128 * 32];

    const int tid  = threadIdx.x;
    const int bidM = blockIdx.x % (M_DIM / 128);
    const int bidN = blockIdx.x / (M_DIM / 128);
    const int tM = bidM * 128;
    const int tN = bidN * 128;
    const int arr = tN >> 10;        // uniform per block (1024 % 128 == 0)
    const int nb  = tN & 1023;       // column base within the selected array

    const float* W    = (arr == 0) ? Wx : (arr == 1) ? Wd : Wg;
    const float* bias = (arr == 0) ? bx : (arr == 1) ? bdl : bg;
    unsigned short* outp = (arr == 0) ? cxw : (arr == 1) ? dw : gw;

    const int lane = tid & 63;
    const int wid  = tid >> 6;
    const int wm = wid >> 1, wn = wid & 1;
    const int lr = lane & 15, lk = lane >> 4;

    f32x4 acc[4][4];
#pragma unroll
    for (int mi = 0; mi < 4; mi++)
#pragma unroll
        for (int ni = 0; ni < 4; ni++)
            acc[mi][ni] = (f32x4){0.f, 0.f, 0.f, 0.f};

    float4 ra[4], rb[4];
    auto ldtiles = [&](int kk) {
        const int k0 = kk * 32;
#pragma unroll
        for (int i = 0; i < 4; i++) {
            int q  = i * 256 + tid;
            int r_ = q >> 3;          // tile row 0..127
            int c4 = (q & 7) << 2;    // k offset 0,4,...,28
            ra[i] = *reinterpret_cast<const float4*>(x + (size_t)(tM + r_) * K_DIM + k0 + c4);
            rb[i] = *reinterpret_cast<const float4*>(W + (size_t)(nb + r_) * K_DIM + k0 + c4);
        }
    };

    ldtiles(0);
    const int NK = K_DIM / 32;
    for (int kk = 0; kk < NK; ++kk) {
        __syncthreads();   // previous iteration's LDS reads done
#pragma unroll
        for (int i = 0; i < 4; i++) {
            int q  = i * 256 + tid;
            int r_ = q >> 3;
            int c4 = (q & 7) << 2;
            us4 wa, wb;
            wa[0] = f2bf(ra[i].x); wa[1] = f2bf(ra[i].y);
            wa[2] = f2bf(ra[i].z); wa[3] = f2bf(ra[i].w);
            wb[0] = f2bf(rb[i].x); wb[1] = f2bf(rb[i].y);
            wb[2] = f2bf(rb[i].z); wb[3] = f2bf(rb[i].w);
            *reinterpret_cast<us4*>(&ldsA[r_ * 32 + c4]) = wa;
            *reinterpret_cast<us4*>(&ldsB[r_ * 32 + c4]) = wb;
        }
        __syncthreads();
        if (kk + 1 < NK) ldtiles(kk + 1);   // overlap next loads with MFMA

        bf16x8 af[4], bfr[4];
#pragma unroll
        for (int mi = 0; mi < 4; mi++)
            af[mi] = *reinterpret_cast<const bf16x8*>(&ldsA[(wm * 64 + mi * 16 + lr) * 32 + lk * 8]);
#pragma unroll
        for (int ni = 0; ni < 4; ni++)
            bfr[ni] = *reinterpret_cast<const bf16x8*>(&ldsB[(wn * 64 + ni * 16 + lr) * 32 + lk * 8]);
#pragma unroll
        for (int mi = 0; mi < 4; mi++)
#pragma unroll
            for (int ni = 0; ni < 4; ni++)
                acc[mi][ni] = __builtin_amdgcn_mfma_f32_16x16x32_bf16(af[mi], bfr[ni], acc[mi][ni], 0, 0, 0);
    }

    // Epilogue: bias + activation + bf16 store.
#pragma unroll
    for (int ni = 0; ni < 4; ni++) {
        int col = nb + wn * 64 + ni * 16 + lr;
        float bia = bias[col];
#pragma unroll
        for (int mi = 0; mi < 4; mi++) {
            int m0 = tM + wm * 64 + mi * 16 + lk * 4;
#pragma unroll
            for (int r = 0; r < 4; r++) {
                float v = acc[mi][ni][r] + bia;
                if (arr == 1)      v = sigmoid_f(v);
                else if (arr == 2) v = v * sigmoid_f(v);
                outp[(size_t)(m0 + r) * D_DIM + col] = f2bf(v);
            }
        }
    }
}

// ---------------------------------------------------------------------------
// Scan pass 1: per (chunk, channel-quad): A = prod(1-d), B = local scan from 0
// (valid for r_h == 0; nonzero channels fixed up by scan_fixup)
// ---------------------------------------------------------------------------
__global__ __launch_bounds__(256)
void scan_pass1(const unsigned short* __restrict__ dw,
                const unsigned short* __restrict__ cxw,
                float* __restrict__ Aw, float* __restrict__ Bw)
{
    int g  = blockIdx.x * 256 + threadIdx.x;   // [0, CHUNKS*BD/4)
    int c  = g / (BD / 4);
    int i0 = (g % (BD / 4)) * 4;
    size_t base = (size_t)c * CLEN * BD + i0;

    float a[4]  = {1.f, 1.f, 1.f, 1.f};
    float hb[4] = {0.f, 0.f, 0.f, 0.f};
    for (int t = 0; t < CLEN; t++) {
        us4 dv = *reinterpret_cast<const us4*>(dw  + base + (size_t)t * BD);
        us4 cv = *reinterpret_cast<const us4*>(cxw + base + (size_t)t * BD);
#pragma unroll
        for (int j = 0; j < 4; j++) {
            float d = bf2f(dv[j]);
            float om = 1.f - d;
            float cand = tanh_f(bf2f(cv[j]));
            hb[j] = om * hb[j] + d * cand;
            a[j] *= om;
        }
    }
    *reinterpret_cast<float4*>(Aw + (size_t)c * BD + i0) = make_float4(a[0], a[1], a[2], a[3]);
    *reinterpret_cast<float4*>(Bw + (size_t)c * BD + i0) = make_float4(hb[0], hb[1], hb[2], hb[3]);
}

// ---------------------------------------------------------------------------
// Scan pass 2: sequential combine over chunks (tiny). Also writes h[0] row.
// ---------------------------------------------------------------------------
__global__ __launch_bounds__(256)
void scan_pass2(const float* __restrict__ Aw, const float* __restrict__ Bw,
                const float* __restrict__ h0, float* __restrict__ hin,
                float* __restrict__ hseq)
{
    int i0 = (blockIdx.x * 256 + threadIdx.x) * 4;  // BD/4 threads
    if (i0 >= BD) return;
    float4 h = *reinterpret_cast<const float4*>(h0 + i0);
    *reinterpret_cast<float4*>(hseq + i0) = h;      // h[0] = h0
    for (int c = 0; c < CHUNKS; c++) {
        *reinterpret_cast<float4*>(hin + (size_t)c * BD + i0) = h;
        float4 A  = *reinterpret_cast<const float4*>(Aw + (size_t)c * BD + i0);
        float4 Bv = *reinterpret_cast<const float4*>(Bw + (size_t)c * BD + i0);
        h.x = A.x * h.x + Bv.x;
        h.y = A.y * h.y + Bv.y;
        h.z = A.z * h.z + Bv.z;
        h.w = A.w * h.w + Bv.w;
    }
}

// ---------------------------------------------------------------------------
// Scan pass 3: replay each chunk with its true h_in; write out and h.
// ---------------------------------------------------------------------------
__global__ __launch_bounds__(256)
void scan_pass3(const unsigned short* __restrict__ dw,
                const unsigned short* __restrict__ cxw,
                const unsigned short* __restrict__ gw,
                const float* __restrict__ hin,
                float* __restrict__ out, float* __restrict__ hseq)
{
    int g  = blockIdx.x * 256 + threadIdx.x;
    int c  = g / (BD / 4);
    int i0 = (g % (BD / 4)) * 4;
    size_t base = (size_t)c * CLEN * BD + i0;

    float4 h4 = *reinterpret_cast<const float4*>(hin + (size_t)c * BD + i0);
    float h[4] = {h4.x, h4.y, h4.z, h4.w};
    for (int t = 0; t < CLEN; t++) {
        size_t idx = base + (size_t)t * BD;
        us4 dv = *reinterpret_cast<const us4*>(dw  + idx);
        us4 cv = *reinterpret_cast<const us4*>(cxw + idx);
        us4 gv = *reinterpret_cast<const us4*>(gw  + idx);
        float o[4];
#pragma unroll
        for (int j = 0; j < 4; j++) {
            float d = bf2f(dv[j]);
            float om = 1.f - d;
            float cand = tanh_f(bf2f(cv[j]));
            h[j] = om * h[j] + d * cand;
            o[j] = h[j] * bf2f(gv[j]);
        }
        *reinterpret_cast<float4*>(out + idx)        = make_float4(o[0], o[1], o[2], o[3]);
        *reinterpret_cast<float4*>(hseq + idx + BD)  = make_float4(h[0], h[1], h[2], h[3]);
    }
}

// ---------------------------------------------------------------------------
// Fixup for channels with r_h != 0: true nonlinear sequential recurrence.
// (r_h == 0 in the provided inputs -> immediate exit, ~µs.)
// ---------------------------------------------------------------------------
__global__ __launch_bounds__(256)
void scan_fixup(const float* __restrict__ rh, const float* __restrict__ h0,
                const unsigned short* __restrict__ dw,
                const unsigned short* __restrict__ cxw,
                const unsigned short* __restrict__ gw,
                float* __restrict__ out, float* __restrict__ hseq)
{
    int i = blockIdx.x * 256 + threadIdx.x;  // BD threads
    if (i >= BD) return;
    float r = rh[i & (D_DIM - 1)];
    if (r == 0.0f) return;
    float h = h0[i];
    for (int t = 0; t < T_DIM; t++) {
        size_t idx = (size_t)t * BD + i;
        float d = bf2f(dw[idx]);
        float cand = tanh_f(bf2f(cxw[idx]) + r * h);
        h = (1.f - d) * h + d * cand;
        out[idx] = h * bf2f(gw[idx]);
        hseq[idx + BD] = h;
    }
}

extern "C" void kernel_launch(void* const* d_in, const int* in_sizes, int n_in,
                              void* d_out, int out_size, void* d_ws, size_t ws_size,
                              hipStream_t stream)
{
    const float* x   = (const float*)d_in[0];
    const float* h0  = (const float*)d_in[1];
    const float* Wx  = (const float*)d_in[2];
    const float* rh  = (const float*)d_in[3];
    const float* Wd  = (const float*)d_in[4];
    const float* Wg  = (const float*)d_in[5];
    const float* bx  = (const float*)d_in[6];
    const float* bdl = (const float*)d_in[7];
    const float* bg  = (const float*)d_in[8];

    float* out  = (float*)d_out;                       // [T,B,D]
    float* hseq = out + (size_t)T_DIM * BD;            // [T+1,B,D]

    // Workspace layout (~214 MB): delta | cand_x | gate (bf16), A | B | hin (f32)
    unsigned short* dw  = (unsigned short*)d_ws;
    unsigned short* cxw = dw  + (size_t)M_DIM * D_DIM;
    unsigned short* gw  = cxw + (size_t)M_DIM * D_DIM;
    float* Aw  = (float*)(gw + (size_t)M_DIM * D_DIM);
    float* Bw  = Aw + (size_t)CHUNKS * BD;
    float* hin = Bw + (size_t)CHUNKS * BD;

    gemm_fused<<<dim3((M_DIM / 128) * (N_DIM / 128)), dim3(256), 0, stream>>>(
        x, Wx, Wd, Wg, bx, bdl, bg, cxw, dw, gw);

    scan_pass1<<<dim3(CHUNKS * BD / 4 / 256), dim3(256), 0, stream>>>(dw, cxw, Aw, Bw);
    scan_pass2<<<dim3(BD / 4 / 256), dim3(256), 0, stream>>>(Aw, Bw, h0, hin, hseq);
    scan_pass3<<<dim3(CHUNKS * BD / 4 / 256), dim3(256), 0, stream>>>(dw, cxw, gw, hin, out, hseq);
    scan_fixup<<<dim3(BD / 256), dim3(256), 0, stream>>>(rh, h0, dw, cxw, gw, out, hseq);
}

// Round 2
// 478.874 us; speedup vs baseline: 1.3048x; 1.3048x over previous
//
#include <hip/hip_runtime.h>
#include <hip/hip_bf16.h>

#define T_DIM 2048
#define B_DIM 16
#define D_DIM 1024
#define M_DIM (T_DIM * B_DIM)   // 32768 GEMM rows
#define K_DIM D_DIM             // 1024
#define N_DIM (3 * D_DIM)       // 3072 (cand_x | delta | gate)
#define BD (B_DIM * D_DIM)      // 16384 parallel chains
#define CHUNKS 64
#define CLEN (T_DIM / CHUNKS)   // 32

typedef __attribute__((ext_vector_type(8))) short bf16x8;
typedef __attribute__((ext_vector_type(4))) float f32x4;
typedef __attribute__((ext_vector_type(4))) unsigned short us4;
typedef __attribute__((ext_vector_type(8))) unsigned short us8;

__device__ __forceinline__ unsigned short f2bf(float f) {
    unsigned int u = __builtin_bit_cast(unsigned int, f);
    u += 0x7fffu + ((u >> 16) & 1u);  // RNE
    return (unsigned short)(u >> 16);
}
__device__ __forceinline__ float bf2f(unsigned short s) {
    unsigned int u = ((unsigned int)s) << 16;
    return __builtin_bit_cast(float, u);
}
__device__ __forceinline__ float sigmoid_f(float x) {
    return __builtin_amdgcn_rcpf(1.0f + __expf(-x));
}
__device__ __forceinline__ float tanh_f(float x) {
    float e = __expf(2.0f * x);
    return 1.0f - 2.0f * __builtin_amdgcn_rcpf(e + 1.0f);
}

__device__ __forceinline__ void gload_lds16(const unsigned short* g, unsigned short* l) {
    __builtin_amdgcn_global_load_lds(
        (const __attribute__((address_space(1))) unsigned int*)g,
        (__attribute__((address_space(3))) unsigned int*)l, 16, 0, 0);
}

// ---------------------------------------------------------------------------
// f32 -> bf16 conversion, 8 elems/thread (32B read, 16B write).
// ---------------------------------------------------------------------------
__global__ __launch_bounds__(256)
void conv_bf16(const float* __restrict__ in, unsigned short* __restrict__ outp, int n8)
{
    int i = blockIdx.x * 256 + threadIdx.x;
    if (i >= n8) return;
    const float4* p = reinterpret_cast<const float4*>(in) + (size_t)i * 2;
    float4 v0 = p[0], v1 = p[1];
    us8 w;
    w[0] = f2bf(v0.x); w[1] = f2bf(v0.y); w[2] = f2bf(v0.z); w[3] = f2bf(v0.w);
    w[4] = f2bf(v1.x); w[5] = f2bf(v1.y); w[6] = f2bf(v1.z); w[7] = f2bf(v1.w);
    *reinterpret_cast<us8*>(outp + (size_t)i * 8) = w;
}

// ---------------------------------------------------------------------------
// Fused projection GEMM (m97 structure): Y[m,n] = sum_k xb[m,k] * Wb[n,k]
// bf16 inputs, global_load_lds width-16 staging, 128x128 tile, BK=64,
// 4 waves (2x2), single LDS buffer, 2 barriers per K-step.
// arr 0: cand_x (identity + b) -> cxw ; arr 1: delta (sigmoid + b_delta) -> dw
// arr 2: gate (silu + b_gate)  -> gw
// ---------------------------------------------------------------------------
__global__ __launch_bounds__(256, 2)
void gemm_fused(const unsigned short* __restrict__ xb,
                const unsigned short* __restrict__ Wb,   // [3][1024][1024]
                const float* __restrict__ bx, const float* __restrict__ bdl,
                const float* __restrict__ bg,
                unsigned short* __restrict__ cxw, unsigned short* __restrict__ dw,
                unsigned short* __restrict__ gw)
{
    __shared__ unsigned short ldsA[128 * 64];   // 16 KB
    __shared__ unsigned short ldsB[128 * 64];   // 16 KB

    const int NWG = (M_DIM / 128) * (N_DIM / 128);   // 6144, %8 == 0
    int bid = blockIdx.x;
    int wg  = (bid & 7) * (NWG / 8) + (bid >> 3);    // XCD-bijective swizzle
    const int bidM = wg % (M_DIM / 128);             // M inner: XCD keeps one W-panel in L2
    const int bidN = wg / (M_DIM / 128);
    const int tM = bidM * 128;
    const int tN = bidN * 128;
    const int arr = tN >> 10;
    const int nb  = tN & 1023;

    const float* bias = (arr == 0) ? bx : (arr == 1) ? bdl : bg;
    unsigned short* outp = (arr == 0) ? cxw : (arr == 1) ? dw : gw;

    const int tid  = threadIdx.x;
    const int lane = tid & 63;
    const int wid  = tid >> 6;
    const int wm = wid >> 1, wn = wid & 1;
    const int lr = lane & 15, lk = lane >> 4;

    const unsigned short* Asrc = xb + (size_t)tM * K_DIM;
    const unsigned short* Bsrc = Wb + (size_t)arr * (D_DIM * K_DIM) + (size_t)nb * K_DIM;

    // per-lane source offsets for global_load_lds (linear LDS dest)
    const int srow = (lane >> 3);          // row within 8-row chunk
    const int ske  = (lane & 7) * 8;       // k-elem offset within 64

    f32x4 acc[4][4];
#pragma unroll
    for (int mi = 0; mi < 4; mi++)
#pragma unroll
        for (int ni = 0; ni < 4; ni++)
            acc[mi][ni] = (f32x4){0.f, 0.f, 0.f, 0.f};

    const int NK = K_DIM / 64;   // 16 K-steps
    for (int kk = 0; kk < NK; ++kk) {
        const int k0 = kk * 64;
#pragma unroll
        for (int i = 0; i < 4; i++) {
            int c   = wid * 4 + i;             // chunk 0..15, 8 rows each
            int row = c * 8 + srow;
            gload_lds16(Asrc + (size_t)row * K_DIM + k0 + ske, &ldsA[c * 512]);
            gload_lds16(Bsrc + (size_t)row * K_DIM + k0 + ske, &ldsB[c * 512]);
        }
        __syncthreads();   // drains vmcnt(0): staged tile visible

#pragma unroll
        for (int kk2 = 0; kk2 < 2; kk2++) {
            bf16x8 af[4], bfr[4];
#pragma unroll
            for (int mi = 0; mi < 4; mi++)
                af[mi] = *reinterpret_cast<const bf16x8*>(
                    &ldsA[(wm * 64 + mi * 16 + lr) * 64 + kk2 * 32 + lk * 8]);
#pragma unroll
            for (int ni = 0; ni < 4; ni++)
                bfr[ni] = *reinterpret_cast<const bf16x8*>(
                    &ldsB[(wn * 64 + ni * 16 + lr) * 64 + kk2 * 32 + lk * 8]);
#pragma unroll
            for (int mi = 0; mi < 4; mi++)
#pragma unroll
                for (int ni = 0; ni < 4; ni++)
                    acc[mi][ni] = __builtin_amdgcn_mfma_f32_16x16x32_bf16(
                        af[mi], bfr[ni], acc[mi][ni], 0, 0, 0);
        }
        __syncthreads();   // all waves done reading before next stage overwrites
    }

    // Epilogue: bias + activation + bf16 store.
#pragma unroll
    for (int ni = 0; ni < 4; ni++) {
        int col = nb + wn * 64 + ni * 16 + lr;
        float bia = bias[col];
#pragma unroll
        for (int mi = 0; mi < 4; mi++) {
            int m0 = tM + wm * 64 + mi * 16 + lk * 4;
#pragma unroll
            for (int r = 0; r < 4; r++) {
                float v = acc[mi][ni][r] + bia;
                if (arr == 1)      v = sigmoid_f(v);
                else if (arr == 2) v = v * sigmoid_f(v);
                outp[(size_t)(m0 + r) * D_DIM + col] = f2bf(v);
            }
        }
    }
}

// ---------------------------------------------------------------------------
// Scan pass 1: per (chunk, channel-quad): A = prod(1-d), B = local scan from 0
// (valid for r_h == 0; nonzero channels fixed up by scan_fixup)
// ---------------------------------------------------------------------------
__global__ __launch_bounds__(256)
void scan_pass1(const unsigned short* __restrict__ dw,
                const unsigned short* __restrict__ cxw,
                float* __restrict__ Aw, float* __restrict__ Bw)
{
    int g  = blockIdx.x * 256 + threadIdx.x;   // [0, CHUNKS*BD/4)
    int c  = g / (BD / 4);
    int i0 = (g % (BD / 4)) * 4;
    size_t base = (size_t)c * CLEN * BD + i0;

    float a[4]  = {1.f, 1.f, 1.f, 1.f};
    float hb[4] = {0.f, 0.f, 0.f, 0.f};
    for (int t = 0; t < CLEN; t++) {
        us4 dv = *reinterpret_cast<const us4*>(dw  + base + (size_t)t * BD);
        us4 cv = *reinterpret_cast<const us4*>(cxw + base + (size_t)t * BD);
#pragma unroll
        for (int j = 0; j < 4; j++) {
            float d = bf2f(dv[j]);
            float om = 1.f - d;
            float cand = tanh_f(bf2f(cv[j]));
            hb[j] = om * hb[j] + d * cand;
            a[j] *= om;
        }
    }
    *reinterpret_cast<float4*>(Aw + (size_t)c * BD + i0) = make_float4(a[0], a[1], a[2], a[3]);
    *reinterpret_cast<float4*>(Bw + (size_t)c * BD + i0) = make_float4(hb[0], hb[1], hb[2], hb[3]);
}

// ---------------------------------------------------------------------------
// Scan pass 2: sequential combine over chunks (tiny). Also writes h[0] row.
// ---------------------------------------------------------------------------
__global__ __launch_bounds__(256)
void scan_pass2(const float* __restrict__ Aw, const float* __restrict__ Bw,
                const float* __restrict__ h0, float* __restrict__ hin,
                float* __restrict__ hseq)
{
    int i0 = (blockIdx.x * 256 + threadIdx.x) * 4;  // BD/4 threads
    if (i0 >= BD) return;
    float4 h = *reinterpret_cast<const float4*>(h0 + i0);
    *reinterpret_cast<float4*>(hseq + i0) = h;      // h[0] = h0
    for (int c = 0; c < CHUNKS; c++) {
        *reinterpret_cast<float4*>(hin + (size_t)c * BD + i0) = h;
        float4 A  = *reinterpret_cast<const float4*>(Aw + (size_t)c * BD + i0);
        float4 Bv = *reinterpret_cast<const float4*>(Bw + (size_t)c * BD + i0);
        h.x = A.x * h.x + Bv.x;
        h.y = A.y * h.y + Bv.y;
        h.z = A.z * h.z + Bv.z;
        h.w = A.w * h.w + Bv.w;
    }
}

// ---------------------------------------------------------------------------
// Scan pass 3: replay each chunk with its true h_in; write out and h.
// ---------------------------------------------------------------------------
__global__ __launch_bounds__(256)
void scan_pass3(const unsigned short* __restrict__ dw,
                const unsigned short* __restrict__ cxw,
                const unsigned short* __restrict__ gw,
                const float* __restrict__ hin,
                float* __restrict__ out, float* __restrict__ hseq)
{
    int g  = blockIdx.x * 256 + threadIdx.x;
    int c  = g / (BD / 4);
    int i0 = (g % (BD / 4)) * 4;
    size_t base = (size_t)c * CLEN * BD + i0;

    float4 h4 = *reinterpret_cast<const float4*>(hin + (size_t)c * BD + i0);
    float h[4] = {h4.x, h4.y, h4.z, h4.w};
    for (int t = 0; t < CLEN; t++) {
        size_t idx = base + (size_t)t * BD;
        us4 dv = *reinterpret_cast<const us4*>(dw  + idx);
        us4 cv = *reinterpret_cast<const us4*>(cxw + idx);
        us4 gv = *reinterpret_cast<const us4*>(gw  + idx);
        float o[4];
#pragma unroll
        for (int j = 0; j < 4; j++) {
            float d = bf2f(dv[j]);
            float om = 1.f - d;
            float cand = tanh_f(bf2f(cv[j]));
            h[j] = om * h[j] + d * cand;
            o[j] = h[j] * bf2f(gv[j]);
        }
        *reinterpret_cast<float4*>(out + idx)        = make_float4(o[0], o[1], o[2], o[3]);
        *reinterpret_cast<float4*>(hseq + idx + BD)  = make_float4(h[0], h[1], h[2], h[3]);
    }
}

// ---------------------------------------------------------------------------
// Fixup for channels with r_h != 0: true nonlinear sequential recurrence.
// (r_h == 0 in the provided inputs -> immediate exit, ~µs.)
// ---------------------------------------------------------------------------
__global__ __launch_bounds__(256)
void scan_fixup(const float* __restrict__ rh, const float* __restrict__ h0,
                const unsigned short* __restrict__ dw,
                const unsigned short* __restrict__ cxw,
                const unsigned short* __restrict__ gw,
                float* __restrict__ out, float* __restrict__ hseq)
{
    int i = blockIdx.x * 256 + threadIdx.x;  // BD threads
    if (i >= BD) return;
    float r = rh[i & (D_DIM - 1)];
    if (r == 0.0f) return;
    float h = h0[i];
    for (int t = 0; t < T_DIM; t++) {
        size_t idx = (size_t)t * BD + i;
        float d = bf2f(dw[idx]);
        float cand = tanh_f(bf2f(cxw[idx]) + r * h);
        h = (1.f - d) * h + d * cand;
        out[idx] = h * bf2f(gw[idx]);
        hseq[idx + BD] = h;
    }
}

extern "C" void kernel_launch(void* const* d_in, const int* in_sizes, int n_in,
                              void* d_out, int out_size, void* d_ws, size_t ws_size,
                              hipStream_t stream)
{
    const float* x   = (const float*)d_in[0];
    const float* h0  = (const float*)d_in[1];
    const float* Wx  = (const float*)d_in[2];
    const float* rh  = (const float*)d_in[3];
    const float* Wd  = (const float*)d_in[4];
    const float* Wg  = (const float*)d_in[5];
    const float* bx  = (const float*)d_in[6];
    const float* bdl = (const float*)d_in[7];
    const float* bg  = (const float*)d_in[8];

    float* out  = (float*)d_out;                       // [T,B,D]
    float* hseq = out + (size_t)T_DIM * BD;            // [T+1,B,D]

    // Workspace layout (~214 MB): delta | cand_x | gate (bf16), A | B | hin (f32)
    unsigned short* dw  = (unsigned short*)d_ws;
    unsigned short* cxw = dw  + (size_t)M_DIM * D_DIM;
    unsigned short* gw  = cxw + (size_t)M_DIM * D_DIM;
    float* Aw  = (float*)(gw + (size_t)M_DIM * D_DIM);
    float* Bw  = Aw + (size_t)CHUNKS * BD;
    float* hin = Bw + (size_t)CHUNKS * BD;

    // bf16 copies of x and W live in the (not-yet-written) out region of d_out:
    // GEMM finishes before scan_pass3 writes `out`. 67.1 MB + 6.3 MB < 134 MB.
    unsigned short* xb = (unsigned short*)d_out;
    unsigned short* Wb = xb + (size_t)M_DIM * K_DIM;   // [3][1024][1024]

    conv_bf16<<<dim3(M_DIM * K_DIM / 8 / 256), dim3(256), 0, stream>>>(x, xb, M_DIM * K_DIM / 8);
    conv_bf16<<<dim3(D_DIM * K_DIM / 8 / 256), dim3(256), 0, stream>>>(Wx, Wb, D_DIM * K_DIM / 8);
    conv_bf16<<<dim3(D_DIM * K_DIM / 8 / 256), dim3(256), 0, stream>>>(Wd, Wb + (size_t)D_DIM * K_DIM, D_DIM * K_DIM / 8);
    conv_bf16<<<dim3(D_DIM * K_DIM / 8 / 256), dim3(256), 0, stream>>>(Wg, Wb + (size_t)2 * D_DIM * K_DIM, D_DIM * K_DIM / 8);

    gemm_fused<<<dim3((M_DIM / 128) * (N_DIM / 128)), dim3(256), 0, stream>>>(
        xb, Wb, bx, bdl, bg, cxw, dw, gw);

    scan_pass1<<<dim3(CHUNKS * BD / 4 / 256), dim3(256), 0, stream>>>(dw, cxw, Aw, Bw);
    scan_pass2<<<dim3(BD / 4 / 256 + 1), dim3(256), 0, stream>>>(Aw, Bw, h0, hin, hseq);
    scan_pass3<<<dim3(CHUNKS * BD / 4 / 256), dim3(256), 0, stream>>>(dw, cxw, gw, hin, out, hseq);
    scan_fixup<<<dim3(BD / 256), dim3(256), 0, stream>>>(rh, h0, dw, cxw, gw, out, hseq);
}

// Round 4
// 464.414 us; speedup vs baseline: 1.3454x; 1.0311x over previous
//
#include <hip/hip_runtime.h>
#include <hip/hip_bf16.h>

#define T_DIM 2048
#define B_DIM 16
#define D_DIM 1024
#define M_DIM (T_DIM * B_DIM)   // 32768 GEMM rows
#define K_DIM D_DIM             // 1024
#define N_DIM (3 * D_DIM)       // 3072 (cand_x | delta | gate)
#define BD (B_DIM * D_DIM)      // 16384 parallel chains
#define CHUNKS 64
#define CLEN (T_DIM / CHUNKS)   // 32
#define NT (K_DIM / 64)         // 16 K-tiles

typedef __attribute__((ext_vector_type(8))) short bf16x8;
typedef __attribute__((ext_vector_type(4))) float f32x4;
typedef __attribute__((ext_vector_type(4))) unsigned short us4;
typedef __attribute__((ext_vector_type(8))) unsigned short us8;

__device__ __forceinline__ unsigned short f2bf(float f) {
    unsigned int u = __builtin_bit_cast(unsigned int, f);
    u += 0x7fffu + ((u >> 16) & 1u);  // RNE
    return (unsigned short)(u >> 16);
}
__device__ __forceinline__ float bf2f(unsigned short s) {
    unsigned int u = ((unsigned int)s) << 16;
    return __builtin_bit_cast(float, u);
}
__device__ __forceinline__ float sigmoid_f(float x) {
    return __builtin_amdgcn_rcpf(1.0f + __expf(-x));
}
__device__ __forceinline__ float tanh_f(float x) {
    float e = __expf(2.0f * x);
    return 1.0f - 2.0f * __builtin_amdgcn_rcpf(e + 1.0f);
}

__device__ __forceinline__ void gload_lds16(const unsigned short* g, unsigned short* l) {
    __builtin_amdgcn_global_load_lds(
        (const __attribute__((address_space(1))) unsigned int*)g,
        (__attribute__((address_space(3))) unsigned int*)l, 16, 0, 0);
}

// swizzled ds_read of one bf16x8 fragment slice from a 128x64 half-slot
__device__ __forceinline__ bf16x8 lds_rd(const unsigned short* lds, int slot, int srow, int kk, int lk) {
    int ce = (((kk * 64) + (lk * 16)) ^ ((srow & 7) << 4)) >> 1;   // byte-swizzle -> elem
    return *reinterpret_cast<const bf16x8*>(lds + slot * 8192 + srow * 64 + ce);
}

// ---------------------------------------------------------------------------
// f32 -> bf16 conversion, 8 elems/thread (nt loads keep fp32 out of L3).
// ---------------------------------------------------------------------------
__global__ __launch_bounds__(256)
void conv_bf16(const float* __restrict__ in, unsigned short* __restrict__ outp, int n8)
{
    int i = blockIdx.x * 256 + threadIdx.x;
    if (i >= n8) return;
    const f32x4* p = reinterpret_cast<const f32x4*>(in) + (size_t)i * 2;
    f32x4 v0 = __builtin_nontemporal_load(p);
    f32x4 v1 = __builtin_nontemporal_load(p + 1);
    us8 w;
    w[0] = f2bf(v0[0]); w[1] = f2bf(v0[1]); w[2] = f2bf(v0[2]); w[3] = f2bf(v0[3]);
    w[4] = f2bf(v1[0]); w[5] = f2bf(v1[1]); w[6] = f2bf(v1[2]); w[7] = f2bf(v1[3]);
    *reinterpret_cast<us8*>(outp + (size_t)i * 8) = w;
}

// ---------------------------------------------------------------------------
// Fused projection GEMM — 256x256 tile, BK=64, 8 waves (2Mx4N), 8-phase
// schedule with counted vmcnt(6), T2 swizzle, setprio around MFMA clusters.
// A = xb [32768 x 1024] bf16; B = Wb [3][1024][1024] bf16 (row = out col).
// ---------------------------------------------------------------------------
__global__ __launch_bounds__(512, 2)
void gemm_fused(const unsigned short* __restrict__ xb,
                const unsigned short* __restrict__ Wb,
                const float* __restrict__ bx, const float* __restrict__ bdl,
                const float* __restrict__ bg,
                unsigned short* __restrict__ cxw, unsigned short* __restrict__ dw,
                unsigned short* __restrict__ gw)
{
    // 4 half-slots x 16KB per operand (ring over halves), 128 KiB total
    __shared__ unsigned short ldsA[4 * 8192];
    __shared__ unsigned short ldsB[4 * 8192];

    const int NWG = (M_DIM / 256) * (N_DIM / 256);   // 1536, %8 == 0
    int bid = blockIdx.x;
    int wg  = (bid & 7) * (NWG / 8) + (bid >> 3);    // XCD-bijective
    const int bidM = wg / 12;                        // M-outer per XCD
    const int bidN = wg % 12;                        // N inner: x-panel L2-resident
    const int tM  = bidM * 256;
    const int tN  = bidN * 256;
    const int arr = tN >> 10;
    const int nb  = tN & 1023;

    const float* bias = (arr == 0) ? bx : (arr == 1) ? bdl : bg;
    unsigned short* outp = (arr == 0) ? cxw : (arr == 1) ? dw : gw;

    const int tid  = threadIdx.x;
    const int lane = tid & 63;
    const int wid  = tid >> 6;
    const int wr = wid >> 2, wc = wid & 3;           // wave -> 128x64 output
    const int lr = lane & 15, lk = lane >> 4;

    const unsigned short* Asrc = xb + (size_t)tM * K_DIM;
    const unsigned short* Bsrc = Wb + (size_t)arr * (D_DIM * K_DIM) + (size_t)nb * K_DIM;

    // staging source geometry (T2 inverse swizzle on the global address)
    const int t8 = tid >> 3;                              // 0..63
    const int ke = (((tid & 7) ^ (t8 & 7)) << 3);         // k-elem offset
    // A storage row s = w*64 + t8 -> global row  r = wrs*128 + (h*4 + s>>5)*16 + (s&15)
    auto arow = [&](int h, int w) {
        int s = w * 64 + t8;
        return ((s >> 4) & 1) * 128 + (h * 4 + (s >> 5)) * 16 + (s & 15);
    };
    const int rA00 = arow(0, 0), rA01 = arow(0, 1);
    const int rA10 = arow(1, 0), rA11 = arow(1, 1);

    auto stA = [&](int t, int r0, int r1, int slot) {
        gload_lds16(Asrc + (size_t)r0 * K_DIM + t * 64 + ke, ldsA + slot * 8192 + wid * 512);
        gload_lds16(Asrc + (size_t)r1 * K_DIM + t * 64 + ke, ldsA + slot * 8192 + 4096 + wid * 512);
    };
    auto stB = [&](int t, int h, int slot) {
        gload_lds16(Bsrc + (size_t)(h * 128 + t8) * K_DIM + t * 64 + ke,      ldsB + slot * 8192 + wid * 512);
        gload_lds16(Bsrc + (size_t)(h * 128 + 64 + t8) * K_DIM + t * 64 + ke, ldsB + slot * 8192 + 4096 + wid * 512);
    };

    f32x4 acc[8][4];
#pragma unroll
    for (int mi = 0; mi < 8; mi++)
#pragma unroll
        for (int ni = 0; ni < 4; ni++)
            acc[mi][ni] = (f32x4){0.f, 0.f, 0.f, 0.f};

    // Prologue: tile0 (4 halves) + tile1 {B0, A0, B1}  => 14 loads/wave
    stA(0, rA00, rA01, 0);
    stA(0, rA10, rA11, 1);
    stB(0, 0, 0);
    stB(0, 1, 1);
    stB(1, 0, 2);
    stA(1, rA00, rA01, 2);
    stB(1, 1, 3);
    asm volatile("s_waitcnt vmcnt(6)" ::: "memory");   // tile0 arrived; 3 halves in flight
    __builtin_amdgcn_s_barrier();

    bf16x8 bf[4][2], af[2][2];

#define LOAD_AF(P, ASLOT)                                                          \
    do {                                                                           \
        _Pragma("unroll") for (int j = 0; j < 2; j++)                              \
            _Pragma("unroll") for (int kk = 0; kk < 2; kk++)                       \
                af[j][kk] = lds_rd(ldsA, (ASLOT),                                  \
                                   ((2 * (P) + j) & 3) * 32 + wr * 16 + lr, kk, lk); \
    } while (0)

#define PHASE_MFMA(P)                                                              \
    do {                                                                           \
        __builtin_amdgcn_s_setprio(1);                                             \
        _Pragma("unroll") for (int j = 0; j < 2; j++)                              \
            _Pragma("unroll") for (int ni = 0; ni < 4; ni++) {                     \
                acc[2 * (P) + j][ni] = __builtin_amdgcn_mfma_f32_16x16x32_bf16(    \
                    af[j][0], bf[ni][0], acc[2 * (P) + j][ni], 0, 0, 0);           \
                acc[2 * (P) + j][ni] = __builtin_amdgcn_mfma_f32_16x16x32_bf16(    \
                    af[j][1], bf[ni][1], acc[2 * (P) + j][ni], 0, 0, 0);           \
            }                                                                      \
        __builtin_amdgcn_s_setprio(0);                                             \
    } while (0)

#define WAIT_LGKM()                                          \
    do {                                                     \
        asm volatile("s_waitcnt lgkmcnt(0)" ::: "memory");   \
        __builtin_amdgcn_sched_barrier(0);                   \
    } while (0)

    for (int kt = 0; kt < NT; ++kt) {
        const int par = kt & 1;
        const int a0 = 2 * par, a1 = 2 * par + 1;
        const int bslot = 2 * par + (wc >> 1);
        const int brow  = (wc & 1) * 64;

        // ---- phase 1: all B frags (8 reads) + A mi0-1 (4 reads); stage A1(kt+1)
#pragma unroll
        for (int ni = 0; ni < 4; ni++)
#pragma unroll
            for (int kk = 0; kk < 2; kk++)
                bf[ni][kk] = lds_rd(ldsB, bslot, brow + ni * 16 + lr, kk, lk);
        LOAD_AF(0, a0);
        if (kt + 1 < NT) stA(kt + 1, rA10, rA11, 2 * (1 - par) + 1);
        __builtin_amdgcn_s_barrier();
        WAIT_LGKM();
        PHASE_MFMA(0);
        __builtin_amdgcn_s_barrier();

        // ---- phase 2: A mi2-3; stage B0(kt+2) into freed B slot
        LOAD_AF(1, a0);
        if (kt + 2 < NT) stB(kt + 2, 0, 2 * par);
        __builtin_amdgcn_s_barrier();
        WAIT_LGKM();
        PHASE_MFMA(1);
        __builtin_amdgcn_s_barrier();

        // ---- phase 3: A mi4-5 (half1); stage A0(kt+2) into freed A0 slot
        LOAD_AF(2, a1);
        if (kt + 2 < NT) stA(kt + 2, rA00, rA01, 2 * par);
        __builtin_amdgcn_s_barrier();
        WAIT_LGKM();
        PHASE_MFMA(2);
        __builtin_amdgcn_s_barrier();

        // ---- phase 4: A mi6-7; stage B1(kt+2); end-of-tile counted vmcnt
        LOAD_AF(3, a1);
        if (kt + 2 < NT) stB(kt + 2, 1, 2 * par + 1);
        if (kt < NT - 2) asm volatile("s_waitcnt vmcnt(6)" ::: "memory");
        else             asm volatile("s_waitcnt vmcnt(0)" ::: "memory");
        __builtin_amdgcn_s_barrier();
        WAIT_LGKM();
        PHASE_MFMA(3);
        __builtin_amdgcn_s_barrier();
    }

    // Epilogue: bias + activation + bf16 store.
#pragma unroll
    for (int ni = 0; ni < 4; ni++) {
        int col = nb + wc * 64 + ni * 16 + lr;
        float bia = bias[col];
#pragma unroll
        for (int mi = 0; mi < 8; mi++) {
            int m0 = tM + wr * 128 + mi * 16 + lk * 4;
#pragma unroll
            for (int r = 0; r < 4; r++) {
                float v = acc[mi][ni][r] + bia;
                if (arr == 1)      v = sigmoid_f(v);
                else if (arr == 2) v = v * sigmoid_f(v);
                outp[(size_t)(m0 + r) * D_DIM + col] = f2bf(v);
            }
        }
    }
#undef LOAD_AF
#undef PHASE_MFMA
#undef WAIT_LGKM
}

// ---------------------------------------------------------------------------
// Scan pass 1: per (chunk, channel-quad): A = prod(1-d), B = local scan from 0
// ---------------------------------------------------------------------------
__global__ __launch_bounds__(256)
void scan_pass1(const unsigned short* __restrict__ dw,
                const unsigned short* __restrict__ cxw,
                float* __restrict__ Aw, float* __restrict__ Bw)
{
    int g  = blockIdx.x * 256 + threadIdx.x;
    int c  = g / (BD / 4);
    int i0 = (g % (BD / 4)) * 4;
    size_t base = (size_t)c * CLEN * BD + i0;

    float a[4]  = {1.f, 1.f, 1.f, 1.f};
    float hb[4] = {0.f, 0.f, 0.f, 0.f};
    for (int t = 0; t < CLEN; t++) {
        us4 dv = *reinterpret_cast<const us4*>(dw  + base + (size_t)t * BD);
        us4 cv = *reinterpret_cast<const us4*>(cxw + base + (size_t)t * BD);
#pragma unroll
        for (int j = 0; j < 4; j++) {
            float d = bf2f(dv[j]);
            float om = 1.f - d;
            float cand = tanh_f(bf2f(cv[j]));
            hb[j] = om * hb[j] + d * cand;
            a[j] *= om;
        }
    }
    f32x4 av = {a[0], a[1], a[2], a[3]};
    f32x4 bv = {hb[0], hb[1], hb[2], hb[3]};
    *reinterpret_cast<f32x4*>(Aw + (size_t)c * BD + i0) = av;
    *reinterpret_cast<f32x4*>(Bw + (size_t)c * BD + i0) = bv;
}

// ---------------------------------------------------------------------------
// Scan pass 2: sequential combine over chunks (tiny). Writes h[0].
// ---------------------------------------------------------------------------
__global__ __launch_bounds__(256)
void scan_pass2(const float* __restrict__ Aw, const float* __restrict__ Bw,
                const float* __restrict__ h0, float* __restrict__ hin,
                float* __restrict__ hseq)
{
    int i0 = (blockIdx.x * 256 + threadIdx.x) * 4;
    if (i0 >= BD) return;
    f32x4 h = *reinterpret_cast<const f32x4*>(h0 + i0);
    *reinterpret_cast<f32x4*>(hseq + i0) = h;
    for (int c = 0; c < CHUNKS; c++) {
        *reinterpret_cast<f32x4*>(hin + (size_t)c * BD + i0) = h;
        f32x4 A  = *reinterpret_cast<const f32x4*>(Aw + (size_t)c * BD + i0);
        f32x4 Bv = *reinterpret_cast<const f32x4*>(Bw + (size_t)c * BD + i0);
        h = A * h + Bv;
    }
}

// ---------------------------------------------------------------------------
// Scan pass 3: replay each chunk with true h_in; nt-store out and h.
// ---------------------------------------------------------------------------
__global__ __launch_bounds__(256)
void scan_pass3(const unsigned short* __restrict__ dw,
                const unsigned short* __restrict__ cxw,
                const unsigned short* __restrict__ gw,
                const float* __restrict__ hin,
                float* __restrict__ out, float* __restrict__ hseq)
{
    int g  = blockIdx.x * 256 + threadIdx.x;
    int c  = g / (BD / 4);
    int i0 = (g % (BD / 4)) * 4;
    size_t base = (size_t)c * CLEN * BD + i0;

    f32x4 h4 = *reinterpret_cast<const f32x4*>(hin + (size_t)c * BD + i0);
    float h[4] = {h4[0], h4[1], h4[2], h4[3]};
    for (int t = 0; t < CLEN; t++) {
        size_t idx = base + (size_t)t * BD;
        us4 dv = *reinterpret_cast<const us4*>(dw  + idx);
        us4 cv = *reinterpret_cast<const us4*>(cxw + idx);
        us4 gv = *reinterpret_cast<const us4*>(gw  + idx);
        f32x4 o, hv;
#pragma unroll
        for (int j = 0; j < 4; j++) {
            float d = bf2f(dv[j]);
            float om = 1.f - d;
            float cand = tanh_f(bf2f(cv[j]));
            h[j] = om * h[j] + d * cand;
            o[j] = h[j] * bf2f(gv[j]);
            hv[j] = h[j];
        }
        __builtin_nontemporal_store(o,  reinterpret_cast<f32x4*>(out + idx));
        __builtin_nontemporal_store(hv, reinterpret_cast<f32x4*>(hseq + idx + BD));
    }
}

// ---------------------------------------------------------------------------
// Fixup for channels with r_h != 0 (r_h == 0 here -> immediate exit).
// ---------------------------------------------------------------------------
__global__ __launch_bounds__(256)
void scan_fixup(const float* __restrict__ rh, const float* __restrict__ h0,
                const unsigned short* __restrict__ dw,
                const unsigned short* __restrict__ cxw,
                const unsigned short* __restrict__ gw,
                float* __restrict__ out, float* __restrict__ hseq)
{
    int i = blockIdx.x * 256 + threadIdx.x;
    if (i >= BD) return;
    float r = rh[i & (D_DIM - 1)];
    if (r == 0.0f) return;
    float h = h0[i];
    for (int t = 0; t < T_DIM; t++) {
        size_t idx = (size_t)t * BD + i;
        float d = bf2f(dw[idx]);
        float cand = tanh_f(bf2f(cxw[idx]) + r * h);
        h = (1.f - d) * h + d * cand;
        out[idx] = h * bf2f(gw[idx]);
        hseq[idx + BD] = h;
    }
}

extern "C" void kernel_launch(void* const* d_in, const int* in_sizes, int n_in,
                              void* d_out, int out_size, void* d_ws, size_t ws_size,
                              hipStream_t stream)
{
    const float* x   = (const float*)d_in[0];
    const float* h0  = (const float*)d_in[1];
    const float* Wx  = (const float*)d_in[2];
    const float* rh  = (const float*)d_in[3];
    const float* Wd  = (const float*)d_in[4];
    const float* Wg  = (const float*)d_in[5];
    const float* bx  = (const float*)d_in[6];
    const float* bdl = (const float*)d_in[7];
    const float* bg  = (const float*)d_in[8];

    float* out  = (float*)d_out;                       // [T,B,D]
    float* hseq = out + (size_t)T_DIM * BD;            // [T+1,B,D]

    unsigned short* dw  = (unsigned short*)d_ws;
    unsigned short* cxw = dw  + (size_t)M_DIM * D_DIM;
    unsigned short* gw  = cxw + (size_t)M_DIM * D_DIM;
    float* Aw  = (float*)(gw + (size_t)M_DIM * D_DIM);
    float* Bw  = Aw + (size_t)CHUNKS * BD;
    float* hin = Bw + (size_t)CHUNKS * BD;

    // bf16 x and W live in the not-yet-written `out` region (GEMM finishes
    // before scan_pass3 writes out). 67.1 MB + 6.3 MB < 134 MB.
    unsigned short* xb = (unsigned short*)d_out;
    unsigned short* Wb = xb + (size_t)M_DIM * K_DIM;

    conv_bf16<<<dim3(M_DIM * K_DIM / 8 / 256), dim3(256), 0, stream>>>(x, xb, M_DIM * K_DIM / 8);
    conv_bf16<<<dim3(D_DIM * K_DIM / 8 / 256), dim3(256), 0, stream>>>(Wx, Wb, D_DIM * K_DIM / 8);
    conv_bf16<<<dim3(D_DIM * K_DIM / 8 / 256), dim3(256), 0, stream>>>(Wd, Wb + (size_t)D_DIM * K_DIM, D_DIM * K_DIM / 8);
    conv_bf16<<<dim3(D_DIM * K_DIM / 8 / 256), dim3(256), 0, stream>>>(Wg, Wb + (size_t)2 * D_DIM * K_DIM, D_DIM * K_DIM / 8);

    gemm_fused<<<dim3((M_DIM / 256) * (N_DIM / 256)), dim3(512), 0, stream>>>(
        xb, Wb, bx, bdl, bg, cxw, dw, gw);

    scan_pass1<<<dim3(CHUNKS * BD / 4 / 256), dim3(256), 0, stream>>>(dw, cxw, Aw, Bw);
    scan_pass2<<<dim3(BD / 4 / 256 + 1), dim3(256), 0, stream>>>(Aw, Bw, h0, hin, hseq);
    scan_pass3<<<dim3(CHUNKS * BD / 4 / 256), dim3(256), 0, stream>>>(dw, cxw, gw, hin, out, hseq);
    scan_fixup<<<dim3(BD / 256), dim3(256), 0, stream>>>(rh, h0, dw, cxw, gw, out, hseq);
}

// Round 5
// 384.541 us; speedup vs baseline: 1.6249x; 1.2077x over previous
//
#include <hip/hip_runtime.h>
#include <hip/hip_bf16.h>

#define T_DIM 2048
#define B_DIM 16
#define D_DIM 1024
#define M_DIM (T_DIM * B_DIM)   // 32768 GEMM rows
#define K_DIM D_DIM             // 1024
#define N_DIM (3 * D_DIM)       // 3072 (cand_x | delta | gate)
#define BD (B_DIM * D_DIM)      // 16384 parallel chains
#define CHUNKS 64
#define CLEN (T_DIM / CHUNKS)   // 32
#define NT (K_DIM / 64)         // 16 K-tiles

typedef __attribute__((ext_vector_type(8))) short bf16x8;
typedef __attribute__((ext_vector_type(4))) float f32x4;
typedef __attribute__((ext_vector_type(4))) unsigned short us4;
typedef __attribute__((ext_vector_type(8))) unsigned short us8;

__device__ __forceinline__ unsigned short f2bf(float f) {
    unsigned int u = __builtin_bit_cast(unsigned int, f);
    u += 0x7fffu + ((u >> 16) & 1u);  // RNE
    return (unsigned short)(u >> 16);
}
__device__ __forceinline__ float bf2f(unsigned short s) {
    unsigned int u = ((unsigned int)s) << 16;
    return __builtin_bit_cast(float, u);
}
__device__ __forceinline__ float sigmoid_f(float x) {
    return __builtin_amdgcn_rcpf(1.0f + __expf(-x));
}
__device__ __forceinline__ float tanh_f(float x) {
    float e = __expf(2.0f * x);
    return 1.0f - 2.0f * __builtin_amdgcn_rcpf(e + 1.0f);
}

__device__ __forceinline__ void gload_lds16(const unsigned short* g, unsigned short* l) {
    __builtin_amdgcn_global_load_lds(
        (const __attribute__((address_space(1))) unsigned int*)g,
        (__attribute__((address_space(3))) unsigned int*)l, 16, 0, 0);
}

// swizzled ds_read of one bf16x8 fragment slice from a 128x64 half-slot
__device__ __forceinline__ bf16x8 lds_rd(const unsigned short* lds, int slot, int srow, int kk, int lk) {
    int ce = (((kk * 64) + (lk * 16)) ^ ((srow & 7) << 4)) >> 1;   // byte-swizzle -> elem
    return *reinterpret_cast<const bf16x8*>(lds + slot * 8192 + srow * 64 + ce);
}

// ---------------------------------------------------------------------------
// f32 -> bf16 conversion, 8 elems/thread (nt loads keep fp32 out of L3).
// ---------------------------------------------------------------------------
__global__ __launch_bounds__(256)
void conv_bf16(const float* __restrict__ in, unsigned short* __restrict__ outp, int n8)
{
    int i = blockIdx.x * 256 + threadIdx.x;
    if (i >= n8) return;
    const f32x4* p = reinterpret_cast<const f32x4*>(in) + (size_t)i * 2;
    f32x4 v0 = __builtin_nontemporal_load(p);
    f32x4 v1 = __builtin_nontemporal_load(p + 1);
    us8 w;
    w[0] = f2bf(v0[0]); w[1] = f2bf(v0[1]); w[2] = f2bf(v0[2]); w[3] = f2bf(v0[3]);
    w[4] = f2bf(v1[0]); w[5] = f2bf(v1[1]); w[6] = f2bf(v1[2]); w[7] = f2bf(v1[3]);
    *reinterpret_cast<us8*>(outp + (size_t)i * 8) = w;
}

// ---------------------------------------------------------------------------
// Fused projection GEMM — 256x256 tile, BK=64, 8 waves (2Mx4N), 8-phase
// schedule with counted vmcnt(6), T2 swizzle, setprio, LDS-staged epilogue.
// A = xb [32768 x 1024] bf16; B = Wb [3][1024][1024] bf16 (row = out col).
// ---------------------------------------------------------------------------
__global__ __launch_bounds__(512, 2)
void gemm_fused(const unsigned short* __restrict__ xb,
                const unsigned short* __restrict__ Wb,
                const float* __restrict__ bx, const float* __restrict__ bdl,
                const float* __restrict__ bg,
                unsigned short* __restrict__ cxw, unsigned short* __restrict__ dw,
                unsigned short* __restrict__ gw)
{
    // 128 KiB LDS: during K-loop 4 half-slots x 16KB per operand;
    // during epilogue the whole thing is one 256x256 bf16 C-tile.
    __shared__ unsigned short lds[8 * 8192];
    unsigned short* ldsA = lds;
    unsigned short* ldsB = lds + 4 * 8192;

    const int NWG = (M_DIM / 256) * (N_DIM / 256);   // 1536, %8 == 0
    int bid = blockIdx.x;
    int wg  = (bid & 7) * (NWG / 8) + (bid >> 3);    // XCD-bijective
    const int bidM = wg / 12;                        // M-outer per XCD
    const int bidN = wg % 12;                        // N inner: x-panel L2-resident
    const int tM  = bidM * 256;
    const int tN  = bidN * 256;
    const int arr = tN >> 10;
    const int nb  = tN & 1023;

    const float* bias = (arr == 0) ? bx : (arr == 1) ? bdl : bg;
    unsigned short* outp = (arr == 0) ? cxw : (arr == 1) ? dw : gw;

    const int tid  = threadIdx.x;
    const int lane = tid & 63;
    const int wid  = tid >> 6;
    const int wr = wid >> 2, wc = wid & 3;           // wave -> 128x64 output
    const int lr = lane & 15, lk = lane >> 4;

    const unsigned short* Asrc = xb + (size_t)tM * K_DIM;
    const unsigned short* Bsrc = Wb + (size_t)arr * (D_DIM * K_DIM) + (size_t)nb * K_DIM;

    // staging source geometry (T2 inverse swizzle on the global address)
    const int t8 = tid >> 3;                              // 0..63
    const int ke = (((tid & 7) ^ (t8 & 7)) << 3);         // k-elem offset
    auto arow = [&](int h, int w) {
        int s = w * 64 + t8;
        return ((s >> 4) & 1) * 128 + (h * 4 + (s >> 5)) * 16 + (s & 15);
    };
    const int rA00 = arow(0, 0), rA01 = arow(0, 1);
    const int rA10 = arow(1, 0), rA11 = arow(1, 1);

    auto stA = [&](int t, int r0, int r1, int slot) {
        gload_lds16(Asrc + (size_t)r0 * K_DIM + t * 64 + ke, ldsA + slot * 8192 + wid * 512);
        gload_lds16(Asrc + (size_t)r1 * K_DIM + t * 64 + ke, ldsA + slot * 8192 + 4096 + wid * 512);
    };
    auto stB = [&](int t, int h, int slot) {
        gload_lds16(Bsrc + (size_t)(h * 128 + t8) * K_DIM + t * 64 + ke,      ldsB + slot * 8192 + wid * 512);
        gload_lds16(Bsrc + (size_t)(h * 128 + 64 + t8) * K_DIM + t * 64 + ke, ldsB + slot * 8192 + 4096 + wid * 512);
    };

    f32x4 acc[8][4];
#pragma unroll
    for (int mi = 0; mi < 8; mi++)
#pragma unroll
        for (int ni = 0; ni < 4; ni++)
            acc[mi][ni] = (f32x4){0.f, 0.f, 0.f, 0.f};

    // Prologue: tile0 (4 halves) + tile1 {B0, A0, B1}  => 14 loads/wave
    stA(0, rA00, rA01, 0);
    stA(0, rA10, rA11, 1);
    stB(0, 0, 0);
    stB(0, 1, 1);
    stB(1, 0, 2);
    stA(1, rA00, rA01, 2);
    stB(1, 1, 3);
    asm volatile("s_waitcnt vmcnt(6)" ::: "memory");   // tile0 arrived; 3 halves in flight
    __builtin_amdgcn_s_barrier();

    bf16x8 bf[4][2], af[2][2];

#define LOAD_AF(P, ASLOT)                                                          \
    do {                                                                           \
        _Pragma("unroll") for (int j = 0; j < 2; j++)                              \
            _Pragma("unroll") for (int kk = 0; kk < 2; kk++)                       \
                af[j][kk] = lds_rd(ldsA, (ASLOT),                                  \
                                   ((2 * (P) + j) & 3) * 32 + wr * 16 + lr, kk, lk); \
    } while (0)

#define PHASE_MFMA(P)                                                              \
    do {                                                                           \
        __builtin_amdgcn_s_setprio(1);                                             \
        _Pragma("unroll") for (int j = 0; j < 2; j++)                              \
            _Pragma("unroll") for (int ni = 0; ni < 4; ni++) {                     \
                acc[2 * (P) + j][ni] = __builtin_amdgcn_mfma_f32_16x16x32_bf16(    \
                    af[j][0], bf[ni][0], acc[2 * (P) + j][ni], 0, 0, 0);           \
                acc[2 * (P) + j][ni] = __builtin_amdgcn_mfma_f32_16x16x32_bf16(    \
                    af[j][1], bf[ni][1], acc[2 * (P) + j][ni], 0, 0, 0);           \
            }                                                                      \
        __builtin_amdgcn_s_setprio(0);                                             \
    } while (0)

#define WAIT_LGKM()                                          \
    do {                                                     \
        asm volatile("s_waitcnt lgkmcnt(0)" ::: "memory");   \
        __builtin_amdgcn_sched_barrier(0);                   \
    } while (0)

    for (int kt = 0; kt < NT; ++kt) {
        const int par = kt & 1;
        const int a0 = 2 * par, a1 = 2 * par + 1;
        const int bslot = 2 * par + (wc >> 1);
        const int brow  = (wc & 1) * 64;

        // ---- phase 1: all B frags (8 reads) + A mi0-1 (4 reads); stage A1(kt+1)
#pragma unroll
        for (int ni = 0; ni < 4; ni++)
#pragma unroll
            for (int kk = 0; kk < 2; kk++)
                bf[ni][kk] = lds_rd(ldsB, bslot, brow + ni * 16 + lr, kk, lk);
        LOAD_AF(0, a0);
        if (kt + 1 < NT) stA(kt + 1, rA10, rA11, 2 * (1 - par) + 1);
        __builtin_amdgcn_s_barrier();
        WAIT_LGKM();
        PHASE_MFMA(0);
        __builtin_amdgcn_s_barrier();

        // ---- phase 2: A mi2-3; stage B0(kt+2) into freed B slot
        LOAD_AF(1, a0);
        if (kt + 2 < NT) stB(kt + 2, 0, 2 * par);
        __builtin_amdgcn_s_barrier();
        WAIT_LGKM();
        PHASE_MFMA(1);
        __builtin_amdgcn_s_barrier();

        // ---- phase 3: A mi4-5 (half1); stage A0(kt+2) into freed A0 slot
        LOAD_AF(2, a1);
        if (kt + 2 < NT) stA(kt + 2, rA00, rA01, 2 * par);
        __builtin_amdgcn_s_barrier();
        WAIT_LGKM();
        PHASE_MFMA(2);
        __builtin_amdgcn_s_barrier();

        // ---- phase 4: A mi6-7; stage B1(kt+2); end-of-tile counted vmcnt
        LOAD_AF(3, a1);
        if (kt + 2 < NT) stB(kt + 2, 1, 2 * par + 1);
        if (kt < NT - 2) asm volatile("s_waitcnt vmcnt(6)" ::: "memory");
        else             asm volatile("s_waitcnt vmcnt(0)" ::: "memory");
        __builtin_amdgcn_s_barrier();
        WAIT_LGKM();
        PHASE_MFMA(3);
        __builtin_amdgcn_s_barrier();
    }

    // ---- Epilogue: bias + activation -> bf16 C-tile in LDS (bank-swizzled),
    //      then fully-coalesced 16B global stores (kills write amplification).
#pragma unroll
    for (int ni = 0; ni < 4; ni++) {
        int lc = wc * 64 + ni * 16 + lr;        // local col 0..255
        float bia = bias[nb + lc];
#pragma unroll
        for (int mi = 0; mi < 8; mi++) {
            int r0 = wr * 128 + mi * 16 + lk * 4;
#pragma unroll
            for (int r = 0; r < 4; r++) {
                float v = acc[mi][ni][r] + bia;
                if (arr == 1)      v = sigmoid_f(v);
                else if (arr == 2) v = v * sigmoid_f(v);
                int row  = r0 + r;
                int byte = (row * 512 + lc * 2) ^ ((row & 7) << 4);
                *reinterpret_cast<unsigned short*>(
                    reinterpret_cast<char*>(lds) + byte) = f2bf(v);
            }
        }
    }
    __syncthreads();
#pragma unroll
    for (int it = 0; it < 16; ++it) {
        int off8 = it * 512 + tid;              // 16B-chunk id, 8192 total
        int row  = off8 >> 5;                   // 32 chunks per 256-col row
        int col8 = (off8 & 31) << 3;
        int byte = (row * 512 + col8 * 2) ^ ((row & 7) << 4);
        us8 v = *reinterpret_cast<const us8*>(reinterpret_cast<char*>(lds) + byte);
        *reinterpret_cast<us8*>(outp + (size_t)(tM + row) * D_DIM + nb + col8) = v;
    }
#undef LOAD_AF
#undef PHASE_MFMA
#undef WAIT_LGKM
}

// ---------------------------------------------------------------------------
// Scan pass 1: per (chunk, channel-quad): A = prod(1-d), B = local scan from 0
// ---------------------------------------------------------------------------
__global__ __launch_bounds__(256)
void scan_pass1(const unsigned short* __restrict__ dw,
                const unsigned short* __restrict__ cxw,
                float* __restrict__ Aw, float* __restrict__ Bw)
{
    int g  = blockIdx.x * 256 + threadIdx.x;
    int c  = g / (BD / 4);
    int i0 = (g % (BD / 4)) * 4;
    size_t base = (size_t)c * CLEN * BD + i0;

    float a[4]  = {1.f, 1.f, 1.f, 1.f};
    float hb[4] = {0.f, 0.f, 0.f, 0.f};
    for (int t = 0; t < CLEN; t++) {
        us4 dv = *reinterpret_cast<const us4*>(dw  + base + (size_t)t * BD);
        us4 cv = *reinterpret_cast<const us4*>(cxw + base + (size_t)t * BD);
#pragma unroll
        for (int j = 0; j < 4; j++) {
            float d = bf2f(dv[j]);
            float om = 1.f - d;
            float cand = tanh_f(bf2f(cv[j]));
            hb[j] = om * hb[j] + d * cand;
            a[j] *= om;
        }
    }
    f32x4 av = {a[0], a[1], a[2], a[3]};
    f32x4 bv = {hb[0], hb[1], hb[2], hb[3]};
    *reinterpret_cast<f32x4*>(Aw + (size_t)c * BD + i0) = av;
    *reinterpret_cast<f32x4*>(Bw + (size_t)c * BD + i0) = bv;
}

// ---------------------------------------------------------------------------
// Scan pass 2: sequential combine over chunks (tiny). Writes h[0].
// ---------------------------------------------------------------------------
__global__ __launch_bounds__(256)
void scan_pass2(const float* __restrict__ Aw, const float* __restrict__ Bw,
                const float* __restrict__ h0, float* __restrict__ hin,
                float* __restrict__ hseq)
{
    int i0 = (blockIdx.x * 256 + threadIdx.x) * 4;
    if (i0 >= BD) return;
    f32x4 h = *reinterpret_cast<const f32x4*>(h0 + i0);
    *reinterpret_cast<f32x4*>(hseq + i0) = h;
    for (int c = 0; c < CHUNKS; c++) {
        *reinterpret_cast<f32x4*>(hin + (size_t)c * BD + i0) = h;
        f32x4 A  = *reinterpret_cast<const f32x4*>(Aw + (size_t)c * BD + i0);
        f32x4 Bv = *reinterpret_cast<const f32x4*>(Bw + (size_t)c * BD + i0);
        h = A * h + Bv;
    }
}

// ---------------------------------------------------------------------------
// Scan pass 3: replay each chunk with true h_in; nt-store out and h.
// ---------------------------------------------------------------------------
__global__ __launch_bounds__(256)
void scan_pass3(const unsigned short* __restrict__ dw,
                const unsigned short* __restrict__ cxw,
                const unsigned short* __restrict__ gw,
                const float* __restrict__ hin,
                float* __restrict__ out, float* __restrict__ hseq)
{
    int g  = blockIdx.x * 256 + threadIdx.x;
    int c  = g / (BD / 4);
    int i0 = (g % (BD / 4)) * 4;
    size_t base = (size_t)c * CLEN * BD + i0;

    f32x4 h4 = *reinterpret_cast<const f32x4*>(hin + (size_t)c * BD + i0);
    float h[4] = {h4[0], h4[1], h4[2], h4[3]};
    for (int t = 0; t < CLEN; t++) {
        size_t idx = base + (size_t)t * BD;
        us4 dv = *reinterpret_cast<const us4*>(dw  + idx);
        us4 cv = *reinterpret_cast<const us4*>(cxw + idx);
        us4 gv = *reinterpret_cast<const us4*>(gw  + idx);
        f32x4 o, hv;
#pragma unroll
        for (int j = 0; j < 4; j++) {
            float d = bf2f(dv[j]);
            float om = 1.f - d;
            float cand = tanh_f(bf2f(cv[j]));
            h[j] = om * h[j] + d * cand;
            o[j] = h[j] * bf2f(gv[j]);
            hv[j] = h[j];
        }
        __builtin_nontemporal_store(o,  reinterpret_cast<f32x4*>(out + idx));
        __builtin_nontemporal_store(hv, reinterpret_cast<f32x4*>(hseq + idx + BD));
    }
}

// ---------------------------------------------------------------------------
// Fixup for channels with r_h != 0 (r_h == 0 here -> immediate exit).
// ---------------------------------------------------------------------------
__global__ __launch_bounds__(256)
void scan_fixup(const float* __restrict__ rh, const float* __restrict__ h0,
                const unsigned short* __restrict__ dw,
                const unsigned short* __restrict__ cxw,
                const unsigned short* __restrict__ gw,
                float* __restrict__ out, float* __restrict__ hseq)
{
    int i = blockIdx.x * 256 + threadIdx.x;
    if (i >= BD) return;
    float r = rh[i & (D_DIM - 1)];
    if (r == 0.0f) return;
    float h = h0[i];
    for (int t = 0; t < T_DIM; t++) {
        size_t idx = (size_t)t * BD + i;
        float d = bf2f(dw[idx]);
        float cand = tanh_f(bf2f(cxw[idx]) + r * h);
        h = (1.f - d) * h + d * cand;
        out[idx] = h * bf2f(gw[idx]);
        hseq[idx + BD] = h;
    }
}

extern "C" void kernel_launch(void* const* d_in, const int* in_sizes, int n_in,
                              void* d_out, int out_size, void* d_ws, size_t ws_size,
                              hipStream_t stream)
{
    const float* x   = (const float*)d_in[0];
    const float* h0  = (const float*)d_in[1];
    const float* Wx  = (const float*)d_in[2];
    const float* rh  = (const float*)d_in[3];
    const float* Wd  = (const float*)d_in[4];
    const float* Wg  = (const float*)d_in[5];
    const float* bx  = (const float*)d_in[6];
    const float* bdl = (const float*)d_in[7];
    const float* bg  = (const float*)d_in[8];

    float* out  = (float*)d_out;                       // [T,B,D]
    float* hseq = out + (size_t)T_DIM * BD;            // [T+1,B,D]

    unsigned short* dw  = (unsigned short*)d_ws;
    unsigned short* cxw = dw  + (size_t)M_DIM * D_DIM;
    unsigned short* gw  = cxw + (size_t)M_DIM * D_DIM;
    float* Aw  = (float*)(gw + (size_t)M_DIM * D_DIM);
    float* Bw  = Aw + (size_t)CHUNKS * BD;
    float* hin = Bw + (size_t)CHUNKS * BD;

    // bf16 x and W live in the not-yet-written `out` region (GEMM finishes
    // before scan_pass3 writes out). 67.1 MB + 6.3 MB < 134 MB.
    unsigned short* xb = (unsigned short*)d_out;
    unsigned short* Wb = xb + (size_t)M_DIM * K_DIM;

    conv_bf16<<<dim3(M_DIM * K_DIM / 8 / 256), dim3(256), 0, stream>>>(x, xb, M_DIM * K_DIM / 8);
    conv_bf16<<<dim3(D_DIM * K_DIM / 8 / 256), dim3(256), 0, stream>>>(Wx, Wb, D_DIM * K_DIM / 8);
    conv_bf16<<<dim3(D_DIM * K_DIM / 8 / 256), dim3(256), 0, stream>>>(Wd, Wb + (size_t)D_DIM * K_DIM, D_DIM * K_DIM / 8);
    conv_bf16<<<dim3(D_DIM * K_DIM / 8 / 256), dim3(256), 0, stream>>>(Wg, Wb + (size_t)2 * D_DIM * K_DIM, D_DIM * K_DIM / 8);

    gemm_fused<<<dim3((M_DIM / 256) * (N_DIM / 256)), dim3(512), 0, stream>>>(
        xb, Wb, bx, bdl, bg, cxw, dw, gw);

    scan_pass1<<<dim3(CHUNKS * BD / 4 / 256), dim3(256), 0, stream>>>(dw, cxw, Aw, Bw);
    scan_pass2<<<dim3(BD / 4 / 256 + 1), dim3(256), 0, stream>>>(Aw, Bw, h0, hin, hseq);
    scan_pass3<<<dim3(CHUNKS * BD / 4 / 256), dim3(256), 0, stream>>>(dw, cxw, gw, hin, out, hseq);
    scan_fixup<<<dim3(BD / 256), dim3(256), 0, stream>>>(rh, h0, dw, cxw, gw, out, hseq);
}